// Round 1
// baseline (2585.892 us; speedup 1.0000x reference)
//
#include <hip/hip_runtime.h>

#define N_NODES 50000
#define N_EDGES 800000
#define CCH 64
#define N_MIX 14

__device__ __forceinline__ float leaky(float x) {
    return fmaxf(x, 0.2f * x);
}

// ---------------- weight prep: fold softmax(alphas) into combined weights ----
// Wcomb[k]: 192x64.  rows 0-63: g*w0*gcn_W ; 64-127: g*w1*sage_Wl ;
//                    128-191: g*(w1*sage_Wr + w3*I)
// bc[k][c] = g*(w0*gcn_b + w1*sage_b + w2*gat_b) ; gscale[k] = g*w2
// g = 0.25 for k>=9 (step-3 outputs averaged directly into out)
__global__ void prep_weights(const float* __restrict__ alphas,
                             const float* __restrict__ gcn_W, const float* __restrict__ gcn_b,
                             const float* __restrict__ sage_Wl, const float* __restrict__ sage_Wr,
                             const float* __restrict__ sage_b, const float* __restrict__ gat_b,
                             float* __restrict__ Wcomb, float* __restrict__ bc,
                             float* __restrict__ gscale) {
    int k = blockIdx.x;
    __shared__ float w[5];
    if (threadIdx.x == 0) {
        float a[5], m = -1e30f, s = 0.f;
        for (int i = 0; i < 5; ++i) { a[i] = alphas[k * 5 + i]; m = fmaxf(m, a[i]); }
        for (int i = 0; i < 5; ++i) { a[i] = __expf(a[i] - m); s += a[i]; }
        for (int i = 0; i < 5; ++i) w[i] = a[i] / s;
    }
    __syncthreads();
    float gamma = (k >= 9) ? 0.25f : 1.0f;
    float w0 = gamma * w[0], w1 = gamma * w[1], w3 = gamma * w[3];
    for (int idx = threadIdx.x; idx < 192 * 64; idx += blockDim.x) {
        int r = idx >> 6, c = idx & 63;
        float v;
        if (r < 64)       v = w0 * gcn_W[k * 4096 + r * 64 + c];
        else if (r < 128) v = w1 * sage_Wl[k * 4096 + (r - 64) * 64 + c];
        else {
            v = w1 * sage_Wr[k * 4096 + (r - 128) * 64 + c];
            if (r - 128 == c) v += w3;
        }
        Wcomb[k * 12288 + idx] = v;
    }
    if (threadIdx.x < 64) {
        int c = threadIdx.x;
        bc[k * 64 + c] = gamma * (w[0] * gcn_b[k * 64 + c] + w[1] * sage_b[k * 64 + c] +
                                  w[2] * gat_b[k * 64 + c]);
    }
    if (threadIdx.x == 0) gscale[k] = gamma * w[2];
}

// ---------------- CSR build ------------------------------------------------
__global__ void count_indeg(const int* __restrict__ ei, int* __restrict__ indeg) {
    int e = blockIdx.x * blockDim.x + threadIdx.x;
    if (e < N_EDGES) atomicAdd(&indeg[ei[N_EDGES + e]], 1);
}

__global__ __launch_bounds__(1024) void scan_deg_kernel(int* __restrict__ indeg,
                                                        int* __restrict__ row_ptr,
                                                        float* __restrict__ dinv,
                                                        float* __restrict__ cntf) {
    __shared__ int sdata[1024];
    __shared__ int carry_s;
    int t = threadIdx.x;
    if (t == 0) carry_s = 0;
    __syncthreads();
    for (int base = 0; base < N_NODES; base += 1024) {
        int v = base + t;
        int val = (v < N_NODES) ? indeg[v] : 0;
        sdata[t] = val;
        __syncthreads();
        for (int off = 1; off < 1024; off <<= 1) {
            int tmp = (t >= off) ? sdata[t - off] : 0;
            __syncthreads();
            if (t >= off) sdata[t] += tmp;
            __syncthreads();
        }
        if (v < N_NODES) {
            row_ptr[v] = carry_s + sdata[t] - val;   // exclusive
            dinv[v] = rsqrtf((float)(val + 1));      // self-looped degree
            cntf[v] = (float)(val > 0 ? val : 1);    // SAGE mean denom
            indeg[v] = 0;                            // reuse as fill counter
        }
        __syncthreads();
        if (t == 1023) carry_s += sdata[1023];
        __syncthreads();
    }
    if (t == 0) row_ptr[N_NODES] = carry_s;
}

__global__ void fill_csr(const int* __restrict__ ei, const int* __restrict__ row_ptr,
                         int* __restrict__ fill_cnt, int* __restrict__ col_idx) {
    int e = blockIdx.x * blockDim.x + threadIdx.x;
    if (e < N_EDGES) {
        int d = ei[N_EDGES + e];
        int pos = row_ptr[d] + atomicAdd(&fill_cnt[d], 1);
        col_idx[pos] = ei[e];
    }
}

// ---------------- fused GCN+SAGE aggregation (k-independent) ---------------
// aggG[v] = dinv[v]*sum(dinv[s]*h[s]) + dinv[v]^2*h[v]   (self loop)
// aggS[v] = sum(h[s]) / cnt[v]
__global__ __launch_bounds__(256) void agg_kernel(const float* __restrict__ h,
                                                  const int* __restrict__ row_ptr,
                                                  const int* __restrict__ col_idx,
                                                  const float* __restrict__ dinv,
                                                  const float* __restrict__ cntf,
                                                  float* __restrict__ aggG,
                                                  float* __restrict__ aggS) {
    int node = blockIdx.x * 4 + (threadIdx.x >> 6);
    int c = threadIdx.x & 63;
    if (node >= N_NODES) return;
    int beg = row_ptr[node], end = row_ptr[node + 1];
    float sG = 0.f, sS = 0.f;
    for (int e = beg; e < end; ++e) {
        int s = col_idx[e];
        float hv = h[s * 64 + c];
        sS += hv;
        sG += dinv[s] * hv;
    }
    float dv = dinv[node];
    aggS[node * 64 + c] = sS / cntf[node];
    aggG[node * 64 + c] = dv * sG + dv * dv * h[node * 64 + c];
}

// ---------------- combined GEMM: target += [G|S|H] @ Wc + bc ---------------
__global__ __launch_bounds__(256) void gemm_combined(const float* __restrict__ G,
                                                     const float* __restrict__ S,
                                                     const float* __restrict__ H,
                                                     const float* __restrict__ Wc,
                                                     const float* __restrict__ bcv,
                                                     float* __restrict__ target) {
    __shared__ float W[192 * 64];
    for (int i = threadIdx.x; i < 192 * 64 / 4; i += 256)
        ((float4*)W)[i] = ((const float4*)Wc)[i];
    __syncthreads();
    int g = threadIdx.x & 7, rw = threadIdx.x >> 3;
    int c0 = g * 8;
    for (int rit = 0; rit < 2; ++rit) {
        int row = blockIdx.x * 64 + rit * 32 + rw;
        if (row < N_NODES) {
            float acc[8];
#pragma unroll
            for (int i = 0; i < 8; ++i) acc[i] = 0.f;
            const float* segs[3] = {G, S, H};
#pragma unroll
            for (int seg = 0; seg < 3; ++seg) {
                const float* X = segs[seg] + row * 64;
                const float* Wp = &W[seg * 4096 + c0];
#pragma unroll 8
                for (int k = 0; k < 64; ++k) {
                    float x = X[k];
                    const float* wr = Wp + k * 64;
                    float4 wa = *(const float4*)wr;
                    float4 wb = *(const float4*)(wr + 4);
                    acc[0] += x * wa.x; acc[1] += x * wa.y;
                    acc[2] += x * wa.z; acc[3] += x * wa.w;
                    acc[4] += x * wb.x; acc[5] += x * wb.y;
                    acc[6] += x * wb.z; acc[7] += x * wb.w;
                }
            }
            float* tp = target + row * 64 + c0;
#pragma unroll
            for (int i = 0; i < 8; ++i) tp[i] += acc[i] + bcv[c0 + i];
        }
    }
}

// ---------------- GAT linear + per-row score dots --------------------------
__global__ __launch_bounds__(256) void gemm_gat(const float* __restrict__ H,
                                                const float* __restrict__ Wg,
                                                const float* __restrict__ avs,
                                                const float* __restrict__ avd,
                                                float* __restrict__ hw,
                                                float* __restrict__ ssrc,
                                                float* __restrict__ sdst) {
    __shared__ float W[64 * 64];
    __shared__ float As[64], Ad[64];
    for (int i = threadIdx.x; i < 64 * 64 / 4; i += 256)
        ((float4*)W)[i] = ((const float4*)Wg)[i];
    if (threadIdx.x < 64) { As[threadIdx.x] = avs[threadIdx.x]; Ad[threadIdx.x] = avd[threadIdx.x]; }
    __syncthreads();
    int g = threadIdx.x & 7, rw = threadIdx.x >> 3;
    int c0 = g * 8;
    for (int rit = 0; rit < 2; ++rit) {
        int row = blockIdx.x * 64 + rit * 32 + rw;
        if (row < N_NODES) {
            float acc[8];
#pragma unroll
            for (int i = 0; i < 8; ++i) acc[i] = 0.f;
            const float* X = H + row * 64;
#pragma unroll 8
            for (int k = 0; k < 64; ++k) {
                float x = X[k];
                const float* wr = &W[k * 64 + c0];
                float4 wa = *(const float4*)wr;
                float4 wb = *(const float4*)(wr + 4);
                acc[0] += x * wa.x; acc[1] += x * wa.y;
                acc[2] += x * wa.z; acc[3] += x * wa.w;
                acc[4] += x * wb.x; acc[5] += x * wb.y;
                acc[6] += x * wb.z; acc[7] += x * wb.w;
            }
            float ps = 0.f, pd = 0.f;
#pragma unroll
            for (int i = 0; i < 8; ++i) {
                hw[row * 64 + c0 + i] = acc[i];
                ps += acc[i] * As[c0 + i];
                pd += acc[i] * Ad[c0 + i];
            }
#pragma unroll
            for (int off = 1; off < 8; off <<= 1) {
                ps += __shfl_xor(ps, off, 64);
                pd += __shfl_xor(pd, off, 64);
            }
            if (g == 0) { ssrc[row] = ps; sdst[row] = pd; }
        }
    }
}

// ---------------- GAT softmax-gather (per-node, in-register max/denom) -----
__global__ __launch_bounds__(256) void gat_gather(const float* __restrict__ hw,
                                                  const float* __restrict__ ssrc,
                                                  const float* __restrict__ sdst,
                                                  const int* __restrict__ row_ptr,
                                                  const int* __restrict__ col_idx,
                                                  const float* __restrict__ gscale, int k,
                                                  float* __restrict__ target) {
    int node = blockIdx.x * 4 + (threadIdx.x >> 6);
    int c = threadIdx.x & 63;
    if (node >= N_NODES) return;
    float sd = sdst[node];
    int beg = row_ptr[node], end = row_ptr[node + 1];
    // pass 1: max over in-edges + self, lanes split edges then reduce
    float m = leaky(ssrc[node] + sd);
    for (int e = beg + c; e < end; e += 64)
        m = fmaxf(m, leaky(ssrc[col_idx[e]] + sd));
#pragma unroll
    for (int off = 1; off < 64; off <<= 1)
        m = fmaxf(m, __shfl_xor(m, off, 64));
    // pass 2: denom + weighted feature sum
    float denom, acc;
    {
        float w = __expf(leaky(ssrc[node] + sd) - m);
        denom = w;
        acc = w * hw[node * 64 + c];
    }
    for (int e = beg; e < end; ++e) {
        int s = col_idx[e];
        float w = __expf(leaky(ssrc[s] + sd) - m);
        denom += w;
        acc += w * hw[s * 64 + c];
    }
    target[node * 64 + c] += gscale[k] * acc / denom;
}

// ---------------- final mean: out += 0.25*(s2+s3+s4) -----------------------
__global__ void final_mean(const float4* __restrict__ s2, const float4* __restrict__ s3,
                           const float4* __restrict__ s4, float4* __restrict__ out) {
    int i = blockIdx.x * blockDim.x + threadIdx.x;
    if (i < N_NODES * CCH / 4) {
        float4 o = out[i], a = s2[i], b = s3[i], c = s4[i];
        o.x += 0.25f * (a.x + b.x + c.x);
        o.y += 0.25f * (a.y + b.y + c.y);
        o.z += 0.25f * (a.z + b.z + c.z);
        o.w += 0.25f * (a.w + b.w + c.w);
        out[i] = o;
    }
}

extern "C" void kernel_launch(void* const* d_in, const int* in_sizes, int n_in,
                              void* d_out, int out_size, void* d_ws, size_t ws_size,
                              hipStream_t stream) {
    const float* x       = (const float*)d_in[0];
    const int*   ei      = (const int*)d_in[1];
    const float* alphas  = (const float*)d_in[2];
    const float* gcn_W   = (const float*)d_in[3];
    const float* gcn_b   = (const float*)d_in[4];
    const float* sage_Wl = (const float*)d_in[5];
    const float* sage_Wr = (const float*)d_in[6];
    const float* sage_b  = (const float*)d_in[7];
    const float* gat_W   = (const float*)d_in[8];
    const float* a_src   = (const float*)d_in[9];
    const float* a_dst   = (const float*)d_in[10];
    const float* gat_b   = (const float*)d_in[11];
    float* out = (float*)d_out;

    char* p = (char*)d_ws;
    auto alloc = [&](size_t bytes) -> char* {
        char* r = p;
        p += (bytes + 255) & ~(size_t)255;
        return r;
    };
    const size_t NC = (size_t)N_NODES * CCH * sizeof(float);
    float* sb[3];
    sb[0] = (float*)alloc(NC);  // s2
    sb[1] = (float*)alloc(NC);  // s3
    sb[2] = (float*)alloc(NC);  // s4
    float* hw    = (float*)alloc(NC);
    float* ssrc  = (float*)alloc(N_NODES * 4);
    float* sdst  = (float*)alloc(N_NODES * 4);
    float* dinv  = (float*)alloc(N_NODES * 4);
    float* cntf  = (float*)alloc(N_NODES * 4);
    int* row_ptr = (int*)alloc((N_NODES + 1) * 4);
    int* col_idx = (int*)alloc((size_t)N_EDGES * 4);
    int* indeg   = (int*)alloc(N_NODES * 4);
    float* Wcomb = (float*)alloc((size_t)N_MIX * 12288 * 4);
    float* bcv   = (float*)alloc(N_MIX * 64 * 4);
    float* gsc   = (float*)alloc(N_MIX * 4);

    size_t used = (size_t)(p - (char*)d_ws);
    bool cached = ws_size >= used + 8 * (NC + 256);
    float* aggG[4];
    float* aggS[4];
    if (cached) {
        for (int i = 0; i < 4; ++i) aggG[i] = (float*)alloc(NC);
        for (int i = 0; i < 4; ++i) aggS[i] = (float*)alloc(NC);
    } else {
        float* g0 = (float*)alloc(NC);
        float* s0 = (float*)alloc(NC);
        for (int i = 0; i < 4; ++i) { aggG[i] = g0; aggS[i] = s0; }
    }

    hipMemsetAsync(indeg, 0, N_NODES * 4, stream);
    hipMemsetAsync(out, 0, NC, stream);
    hipMemsetAsync(sb[0], 0, NC, stream);
    hipMemsetAsync(sb[1], 0, NC, stream);
    hipMemsetAsync(sb[2], 0, NC, stream);

    prep_weights<<<N_MIX, 256, 0, stream>>>(alphas, gcn_W, gcn_b, sage_Wl, sage_Wr,
                                            sage_b, gat_b, Wcomb, bcv, gsc);
    count_indeg<<<(N_EDGES + 255) / 256, 256, 0, stream>>>(ei, indeg);
    scan_deg_kernel<<<1, 1024, 0, stream>>>(indeg, row_ptr, dinv, cntf);
    fill_csr<<<(N_EDGES + 255) / 256, 256, 0, stream>>>(ei, row_ptr, indeg, col_idx);

    const int AGG_GRID  = (N_NODES + 3) / 4;      // 12500
    const int GEMM_GRID = (N_NODES + 63) / 64;    // 782

    int offset = 0;
    bool aggDone[4] = {false, false, false, false};
    for (int i = 0; i < 4; ++i) {
        float* target = (i < 3) ? sb[i] : out;
        for (int hi = 0; hi <= i; ++hi) {
            const float* h = (hi == 0) ? x : sb[hi - 1];
            float* aG = aggG[hi];
            float* aS = aggS[hi];
            if (!cached || !aggDone[hi]) {
                agg_kernel<<<AGG_GRID, 256, 0, stream>>>(h, row_ptr, col_idx, dinv, cntf, aG, aS);
                aggDone[hi] = true;
            }
            int js[2];
            int nj = (hi == 0) ? 2 : 1;
            js[0] = (hi == 0) ? 0 : (hi + 1);
            js[1] = 1;
            for (int t = 0; t < nj; ++t) {
                int k = offset + js[t];
                gemm_combined<<<GEMM_GRID, 256, 0, stream>>>(
                    aG, aS, h, Wcomb + (size_t)k * 12288, bcv + k * 64, target);
                gemm_gat<<<GEMM_GRID, 256, 0, stream>>>(
                    h, gat_W + (size_t)k * 4096, a_src + k * 64, a_dst + k * 64, hw, ssrc, sdst);
                gat_gather<<<AGG_GRID, 256, 0, stream>>>(
                    hw, ssrc, sdst, row_ptr, col_idx, gsc, k, target);
            }
        }
        offset += i + 2;
    }

    final_mean<<<(N_NODES * CCH / 4 + 255) / 256, 256, 0, stream>>>(
        (const float4*)sb[0], (const float4*)sb[1], (const float4*)sb[2], (float4*)out);
}

// Round 2
// 1244.732 us; speedup vs baseline: 2.0775x; 2.0775x over previous
//
#include <hip/hip_runtime.h>

#define N_NODES 50000
#define N_EDGES 800000
#define CCH 64
#define N_MIX 14

__device__ __forceinline__ float leaky(float x) {
    return fmaxf(x, 0.2f * x);
}

// ---------------- weight prep --------------------------------------------
// Per k: Wc[k] 192x64 = [g*w0*gcn_W ; g*w1*sage_Wl ; g*(w1*sage_Wr + w3*I)]
//        bc[k]  = g*(w0*gcn_b + w1*sage_b + w2*gat_b)
//        Wg[k]  = g*w2*gat_W   (gscale folded)
//        vs[k]  = gat_W @ a_src (row dots), vd[k] = gat_W @ a_dst  (UNscaled)
// g = 0.25 for k>=9 (final mean folded).
__global__ void prep_weights(const float* __restrict__ alphas,
                             const float* __restrict__ gcn_W, const float* __restrict__ gcn_b,
                             const float* __restrict__ sage_Wl, const float* __restrict__ sage_Wr,
                             const float* __restrict__ sage_b, const float* __restrict__ gat_Wp,
                             const float* __restrict__ a_src, const float* __restrict__ a_dst,
                             const float* __restrict__ gat_b,
                             float* __restrict__ Wc, float* __restrict__ bc,
                             float* __restrict__ Wg, float* __restrict__ vs,
                             float* __restrict__ vd) {
    int k = blockIdx.x;
    __shared__ float w[5];
    if (threadIdx.x == 0) {
        float a[5], m = -1e30f, s = 0.f;
        for (int i = 0; i < 5; ++i) { a[i] = alphas[k * 5 + i]; m = fmaxf(m, a[i]); }
        for (int i = 0; i < 5; ++i) { a[i] = __expf(a[i] - m); s += a[i]; }
        for (int i = 0; i < 5; ++i) w[i] = a[i] / s;
    }
    __syncthreads();
    float gamma = (k >= 9) ? 0.25f : 1.0f;
    float w0 = gamma * w[0], w1 = gamma * w[1], w2g = gamma * w[2], w3 = gamma * w[3];
    for (int idx = threadIdx.x; idx < 192 * 64; idx += blockDim.x) {
        int r = idx >> 6, c = idx & 63;
        float v;
        if (r < 64)       v = w0 * gcn_W[k * 4096 + r * 64 + c];
        else if (r < 128) v = w1 * sage_Wl[k * 4096 + (r - 64) * 64 + c];
        else {
            v = w1 * sage_Wr[k * 4096 + (r - 128) * 64 + c];
            if (r - 128 == c) v += w3;
        }
        Wc[(size_t)k * 12288 + idx] = v;
    }
    for (int idx = threadIdx.x; idx < 4096; idx += blockDim.x)
        Wg[(size_t)k * 4096 + idx] = w2g * gat_Wp[k * 4096 + idx];
    if (threadIdx.x < 64) {
        int r = threadIdx.x;
        bc[k * 64 + r] = gamma * (w[0] * gcn_b[k * 64 + r] + w[1] * sage_b[k * 64 + r] +
                                  w[2] * gat_b[k * 64 + r]);
        float s1 = 0.f, s2 = 0.f;
        for (int j = 0; j < 64; ++j) {
            float wv_ = gat_Wp[k * 4096 + r * 64 + j];
            s1 += wv_ * a_src[k * 64 + j];
            s2 += wv_ * a_dst[k * 64 + j];
        }
        vs[k * 64 + r] = s1;
        vd[k * 64 + r] = s2;
    }
}

// pair sums for the 4 x-state pairs (k0,k0+1), k0 in {0,2,5,9}
__global__ void pair_weights(const float* __restrict__ Wc, const float* __restrict__ bc,
                             float* __restrict__ Wcp, float* __restrict__ bcp) {
    int p = blockIdx.x;
    int k0 = (0x9520 >> (p * 4)) & 15;
    for (int idx = threadIdx.x; idx < 12288; idx += blockDim.x)
        Wcp[(size_t)p * 12288 + idx] =
            Wc[(size_t)k0 * 12288 + idx] + Wc[(size_t)(k0 + 1) * 12288 + idx];
    if (threadIdx.x < 64)
        bcp[p * 64 + threadIdx.x] = bc[k0 * 64 + threadIdx.x] + bc[(k0 + 1) * 64 + threadIdx.x];
}

// ---------------- CSR build ------------------------------------------------
__global__ void count_indeg(const int* __restrict__ ei, int* __restrict__ indeg) {
    int e = blockIdx.x * blockDim.x + threadIdx.x;
    if (e < N_EDGES) atomicAdd(&indeg[ei[N_EDGES + e]], 1);
}

#define NBLK 196  // ceil(50000/256)

__global__ __launch_bounds__(256) void deg_block_reduce(const int* __restrict__ indeg,
                                                        int* __restrict__ bsum) {
    int i = blockIdx.x * 256 + threadIdx.x;
    int v = (i < N_NODES) ? indeg[i] : 0;
#pragma unroll
    for (int off = 1; off < 64; off <<= 1) v += __shfl_xor(v, off, 64);
    __shared__ int ws_[4];
    if ((threadIdx.x & 63) == 0) ws_[threadIdx.x >> 6] = v;
    __syncthreads();
    if (threadIdx.x == 0) bsum[blockIdx.x] = ws_[0] + ws_[1] + ws_[2] + ws_[3];
}

__global__ __launch_bounds__(256) void scan_bsum(int* __restrict__ bsum, int* __restrict__ row_ptr) {
    __shared__ int s[256];
    int t = threadIdx.x;
    int v = (t < NBLK) ? bsum[t] : 0;
    s[t] = v;
    __syncthreads();
    for (int off = 1; off < 256; off <<= 1) {
        int tmp = (t >= off) ? s[t - off] : 0;
        __syncthreads();
        s[t] += tmp;
        __syncthreads();
    }
    if (t < NBLK) bsum[t] = s[t] - v;  // exclusive
    if (t == 0) row_ptr[N_NODES] = s[255];
}

__global__ __launch_bounds__(256) void scan_write(int* __restrict__ indeg,
                                                  const int* __restrict__ bsum,
                                                  int* __restrict__ row_ptr,
                                                  float* __restrict__ dinv,
                                                  float* __restrict__ cntf) {
    int i = blockIdx.x * 256 + threadIdx.x;
    int lane = threadIdx.x & 63, wv = threadIdx.x >> 6;
    int val = (i < N_NODES) ? indeg[i] : 0;
    int inc = val;
#pragma unroll
    for (int off = 1; off < 64; off <<= 1) {
        int t2 = __shfl_up(inc, off, 64);
        if (lane >= off) inc += t2;
    }
    __shared__ int wsum[4];
    if (lane == 63) wsum[wv] = inc;
    __syncthreads();
    int woff = 0;
    for (int j = 0; j < wv; ++j) woff += wsum[j];
    if (i < N_NODES) {
        row_ptr[i] = bsum[blockIdx.x] + woff + inc - val;
        dinv[i] = rsqrtf((float)(val + 1));
        cntf[i] = (float)(val > 0 ? val : 1);
        indeg[i] = 0;  // reuse as fill counter
    }
}

__global__ void fill_csr(const int* __restrict__ ei, const int* __restrict__ row_ptr,
                         int* __restrict__ fill_cnt, int* __restrict__ col_idx) {
    int e = blockIdx.x * blockDim.x + threadIdx.x;
    if (e < N_EDGES) {
        int d = ei[N_EDGES + e];
        int pos = row_ptr[d] + atomicAdd(&fill_cnt[d], 1);
        col_idx[pos] = ei[e];
    }
}

// ---------------- per-state GAT scores: ssrcS[node*snk+t] = h[node]·vs_k ---
template <int NK>
__global__ __launch_bounds__(256) void score_kernel(const float* __restrict__ h,
                                                    const float* __restrict__ vs_all,
                                                    const float* __restrict__ vd_all,
                                                    unsigned kmap,
                                                    float* __restrict__ ssrcS,
                                                    float* __restrict__ sdstS) {
    int node = blockIdx.x * 4 + (threadIdx.x >> 6);
    int lane = threadIdx.x & 63;
    if (node >= N_NODES) return;
    float hv = h[(size_t)node * 64 + lane];
#pragma unroll
    for (int t = 0; t < NK; ++t) {
        int k = (kmap >> (4 * t)) & 15;
        float ps = hv * vs_all[k * 64 + lane];
        float pd = hv * vd_all[k * 64 + lane];
#pragma unroll
        for (int off = 1; off < 64; off <<= 1) {
            ps += __shfl_xor(ps, off, 64);
            pd += __shfl_xor(pd, off, 64);
        }
        if (lane == 0) {
            ssrcS[(size_t)node * NK + t] = ps;
            sdstS[(size_t)node * NK + t] = pd;
        }
    }
}

// ---------------- fused per-state gather: GCN + SAGE + NK GAT softmax ------
// One wave per node, lane = channel. Edge chunks of 64: lane-parallel preload
// of col/dinv/softmax-weight, then shuffle-broadcast feature loop (pipelined
// independent h-row loads).
template <int NK>
__global__ __launch_bounds__(256) void fused_gather(
    const float* __restrict__ h, const int* __restrict__ row_ptr,
    const int* __restrict__ col_idx, const float* __restrict__ dinv,
    const float* __restrict__ cntf, const float* __restrict__ ssrcS,
    const float* __restrict__ sdstS, int snk, int soff, int doGS,
    float* __restrict__ aggG, float* __restrict__ aggS, float* __restrict__ A) {
    int node = blockIdx.x * 4 + (threadIdx.x >> 6);
    int lane = threadIdx.x & 63;
    if (node >= N_NODES) return;
    int beg = row_ptr[node], end = row_ptr[node + 1];
    float sd[NK], m[NK];
#pragma unroll
    for (int t = 0; t < NK; ++t) {
        sd[t] = sdstS[(size_t)node * snk + soff + t];
        m[t] = leaky(ssrcS[(size_t)node * snk + soff + t] + sd[t]);  // self score
    }
    // pass A: per-k max over in-edges (lane-strided)
    for (int e = beg + lane; e < end; e += 64) {
        int s = col_idx[e];
        const float* sp = ssrcS + (size_t)s * snk + soff;
#pragma unroll
        for (int t = 0; t < NK; ++t) m[t] = fmaxf(m[t], leaky(sp[t] + sd[t]));
    }
#pragma unroll
    for (int t = 0; t < NK; ++t)
#pragma unroll
        for (int off = 1; off < 64; off <<= 1) m[t] = fmaxf(m[t], __shfl_xor(m[t], off, 64));
    // self contributions
    float hvself = h[(size_t)node * 64 + lane];
    float denom[NK], acc[NK];
#pragma unroll
    for (int t = 0; t < NK; ++t) {
        float w = __expf(leaky(ssrcS[(size_t)node * snk + soff + t] + sd[t]) - m[t]);
        denom[t] = w;
        acc[t] = w * hvself;
    }
    float sG = 0.f, sS = 0.f;
    for (int base = beg; base < end; base += 64) {
        int cnt = min(64, end - base);
        int col = 0;
        float dv = 0.f, wv[NK];
#pragma unroll
        for (int t = 0; t < NK; ++t) wv[t] = 0.f;
        if (lane < cnt) {
            col = col_idx[base + lane];
            dv = dinv[col];
            const float* sp = ssrcS + (size_t)col * snk + soff;
#pragma unroll
            for (int t = 0; t < NK; ++t) wv[t] = __expf(leaky(sp[t] + sd[t]) - m[t]);
        }
#pragma unroll
        for (int t = 0; t < NK; ++t) {
            float w = wv[t];
#pragma unroll
            for (int off = 1; off < 64; off <<= 1) w += __shfl_xor(w, off, 64);
            denom[t] += w;
        }
        for (int j = 0; j < cnt; ++j) {
            int s = __shfl(col, j, 64);
            float hv = h[(size_t)s * 64 + lane];
            sS += hv;
            sG += __shfl(dv, j, 64) * hv;
#pragma unroll
            for (int t = 0; t < NK; ++t) acc[t] += __shfl(wv[t], j, 64) * hv;
        }
    }
    if (doGS) {
        float dvn = dinv[node];
        aggS[(size_t)node * 64 + lane] = sS / cntf[node];
        aggG[(size_t)node * 64 + lane] = dvn * sG + dvn * dvn * hvself;
    }
#pragma unroll
    for (int t = 0; t < NK; ++t)
        A[(size_t)t * N_NODES * 64 + (size_t)node * 64 + lane] = acc[t] / denom[t];
}

// ---------------- combined GEMM: target += [G|S|H] @ Wc + bc ---------------
__global__ __launch_bounds__(256) void gemm_combined(const float* __restrict__ G,
                                                     const float* __restrict__ S,
                                                     const float* __restrict__ H,
                                                     const float* __restrict__ Wcv,
                                                     const float* __restrict__ bcv,
                                                     float* __restrict__ target) {
    __shared__ float W[192 * 64];
    for (int i = threadIdx.x; i < 192 * 64 / 4; i += 256)
        ((float4*)W)[i] = ((const float4*)Wcv)[i];
    __syncthreads();
    int g = threadIdx.x & 7, rw = threadIdx.x >> 3;
    int c0 = g * 8;
    for (int rit = 0; rit < 2; ++rit) {
        int row = blockIdx.x * 64 + rit * 32 + rw;
        if (row < N_NODES) {
            float acc[8];
#pragma unroll
            for (int i = 0; i < 8; ++i) acc[i] = 0.f;
            const float* segs[3] = {G, S, H};
#pragma unroll
            for (int seg = 0; seg < 3; ++seg) {
                const float* X = segs[seg] + (size_t)row * 64;
                const float* Wp = &W[seg * 4096 + c0];
#pragma unroll 8
                for (int k = 0; k < 64; ++k) {
                    float x = X[k];
                    const float* wr = Wp + k * 64;
                    float4 wa = *(const float4*)wr;
                    float4 wb = *(const float4*)(wr + 4);
                    acc[0] += x * wa.x; acc[1] += x * wa.y;
                    acc[2] += x * wa.z; acc[3] += x * wa.w;
                    acc[4] += x * wb.x; acc[5] += x * wb.y;
                    acc[6] += x * wb.z; acc[7] += x * wb.w;
                }
            }
            float* tp = target + (size_t)row * 64 + c0;
#pragma unroll
            for (int i = 0; i < 8; ++i) tp[i] += acc[i] + bcv[c0 + i];
        }
    }
}

// ---------------- GAT output GEMM: target += sum_s A_s @ Wg_s --------------
template <int NA>
__global__ __launch_bounds__(256) void gemm_gatout(const float* __restrict__ A,
                                                   const float* __restrict__ Wg0,
                                                   const float* __restrict__ Wg1,
                                                   float* __restrict__ target) {
    __shared__ float W[NA * 4096];
    for (int i = threadIdx.x; i < NA * 1024; i += 256)
        ((float4*)W)[i] = (i < 1024) ? ((const float4*)Wg0)[i] : ((const float4*)Wg1)[i - 1024];
    __syncthreads();
    int g = threadIdx.x & 7, rw = threadIdx.x >> 3;
    int c0 = g * 8;
    for (int rit = 0; rit < 2; ++rit) {
        int row = blockIdx.x * 64 + rit * 32 + rw;
        if (row < N_NODES) {
            float acc[8];
#pragma unroll
            for (int i = 0; i < 8; ++i) acc[i] = 0.f;
#pragma unroll
            for (int s = 0; s < NA; ++s) {
                const float* X = A + (size_t)s * N_NODES * 64 + (size_t)row * 64;
                const float* Wp = &W[s * 4096 + c0];
#pragma unroll 8
                for (int k = 0; k < 64; ++k) {
                    float x = X[k];
                    const float* wr = Wp + k * 64;
                    float4 wa = *(const float4*)wr;
                    float4 wb = *(const float4*)(wr + 4);
                    acc[0] += x * wa.x; acc[1] += x * wa.y;
                    acc[2] += x * wa.z; acc[3] += x * wa.w;
                    acc[4] += x * wb.x; acc[5] += x * wb.y;
                    acc[6] += x * wb.z; acc[7] += x * wb.w;
                }
            }
            float* tp = target + (size_t)row * 64 + c0;
#pragma unroll
            for (int i = 0; i < 8; ++i) tp[i] += acc[i];
        }
    }
}

// ---------------- final mean: out += 0.25*(s2+s3+s4) -----------------------
__global__ void final_mean(const float4* __restrict__ s2, const float4* __restrict__ s3,
                           const float4* __restrict__ s4, float4* __restrict__ out) {
    int i = blockIdx.x * blockDim.x + threadIdx.x;
    if (i < N_NODES * CCH / 4) {
        float4 o = out[i], a = s2[i], b = s3[i], c = s4[i];
        o.x += 0.25f * (a.x + b.x + c.x);
        o.y += 0.25f * (a.y + b.y + c.y);
        o.z += 0.25f * (a.z + b.z + c.z);
        o.w += 0.25f * (a.w + b.w + c.w);
        out[i] = o;
    }
}

extern "C" void kernel_launch(void* const* d_in, const int* in_sizes, int n_in,
                              void* d_out, int out_size, void* d_ws, size_t ws_size,
                              hipStream_t stream) {
    const float* x       = (const float*)d_in[0];
    const int*   ei      = (const int*)d_in[1];
    const float* alphas  = (const float*)d_in[2];
    const float* gcn_W   = (const float*)d_in[3];
    const float* gcn_b   = (const float*)d_in[4];
    const float* sage_Wl = (const float*)d_in[5];
    const float* sage_Wr = (const float*)d_in[6];
    const float* sage_b  = (const float*)d_in[7];
    const float* gat_W   = (const float*)d_in[8];
    const float* a_src   = (const float*)d_in[9];
    const float* a_dst   = (const float*)d_in[10];
    const float* gat_b   = (const float*)d_in[11];
    float* out = (float*)d_out;

    char* p = (char*)d_ws;
    auto alloc = [&](size_t bytes) -> char* {
        char* r = p;
        p += (bytes + 255) & ~(size_t)255;
        return r;
    };
    const size_t NC = (size_t)N_NODES * CCH * sizeof(float);
    const size_t NCf = (size_t)N_NODES * CCH;
    float* sb[3];
    sb[0] = (float*)alloc(NC);
    sb[1] = (float*)alloc(NC);
    sb[2] = (float*)alloc(NC);
    float* aggG  = (float*)alloc(NC);
    float* aggS  = (float*)alloc(NC);
    float* ssrcS = (float*)alloc((size_t)N_NODES * 8 * 4);
    float* sdstS = (float*)alloc((size_t)N_NODES * 8 * 4);
    float* dinv  = (float*)alloc(N_NODES * 4);
    float* cntf  = (float*)alloc(N_NODES * 4);
    int* row_ptr = (int*)alloc((N_NODES + 1) * 4);
    int* col_idx = (int*)alloc((size_t)N_EDGES * 4);
    int* indeg   = (int*)alloc(N_NODES * 4);
    int* bsum    = (int*)alloc(NBLK * 4);
    float* Wc    = (float*)alloc((size_t)N_MIX * 12288 * 4);
    float* bcv   = (float*)alloc(N_MIX * 64 * 4);
    float* Wcp   = (float*)alloc((size_t)4 * 12288 * 4);
    float* bcp   = (float*)alloc(4 * 64 * 4);
    float* Wg    = (float*)alloc((size_t)N_MIX * 4096 * 4);
    float* vs    = (float*)alloc(N_MIX * 64 * 4);
    float* vd    = (float*)alloc(N_MIX * 64 * 4);

    size_t used = (size_t)(p - (char*)d_ws);
    int navail = (int)((ws_size > used) ? ((ws_size - used) / NC) : 0);
    if (navail < 1) navail = 1;   // previous-round footprint guarantees >= 1
    if (navail > 8) navail = 8;
    float* Abuf = (float*)alloc((size_t)navail * NC);

    hipMemsetAsync(indeg, 0, N_NODES * 4, stream);
    hipMemsetAsync(out, 0, NC, stream);
    hipMemsetAsync(sb[0], 0, NC, stream);
    hipMemsetAsync(sb[1], 0, NC, stream);
    hipMemsetAsync(sb[2], 0, NC, stream);

    prep_weights<<<N_MIX, 256, 0, stream>>>(alphas, gcn_W, gcn_b, sage_Wl, sage_Wr, sage_b,
                                            gat_W, a_src, a_dst, gat_b, Wc, bcv, Wg, vs, vd);
    pair_weights<<<4, 256, 0, stream>>>(Wc, bcv, Wcp, bcp);
    count_indeg<<<(N_EDGES + 255) / 256, 256, 0, stream>>>(ei, indeg);
    deg_block_reduce<<<NBLK, 256, 0, stream>>>(indeg, bsum);
    scan_bsum<<<1, 256, 0, stream>>>(bsum, row_ptr);
    scan_write<<<NBLK, 256, 0, stream>>>(indeg, bsum, row_ptr, dinv, cntf);
    fill_csr<<<(N_EDGES + 255) / 256, 256, 0, stream>>>(ei, row_ptr, indeg, col_idx);

    const int AGG_GRID = (N_NODES + 3) / 4;     // 12500
    const int GEMM_GRID = (N_NODES + 63) / 64;  // 782

    float* targ[4] = {sb[0], sb[1], sb[2], out};
    struct Phase { int nk; int ks[8]; int tg[8]; };
    const Phase ph[4] = {
        {8, {0, 1, 2, 3, 5, 6, 9, 10}, {0, 0, 1, 1, 2, 2, 3, 3}},
        {3, {4, 7, 11, 0, 0, 0, 0, 0}, {1, 2, 3, 0, 0, 0, 0, 0}},
        {2, {8, 12, 0, 0, 0, 0, 0, 0}, {2, 3, 0, 0, 0, 0, 0, 0}},
        {1, {13, 0, 0, 0, 0, 0, 0, 0}, {3, 0, 0, 0, 0, 0, 0, 0}},
    };

    for (int st = 0; st < 4; ++st) {
        const Phase& P = ph[st];
        const float* h = (st == 0) ? x : sb[st - 1];
        unsigned kmapAll = 0;
        for (int t = 0; t < P.nk; ++t) kmapAll |= (unsigned)P.ks[t] << (4 * t);
        switch (P.nk) {
            case 8: score_kernel<8><<<AGG_GRID, 256, 0, stream>>>(h, vs, vd, kmapAll, ssrcS, sdstS); break;
            case 3: score_kernel<3><<<AGG_GRID, 256, 0, stream>>>(h, vs, vd, kmapAll, ssrcS, sdstS); break;
            case 2: score_kernel<2><<<AGG_GRID, 256, 0, stream>>>(h, vs, vd, kmapAll, ssrcS, sdstS); break;
            default: score_kernel<1><<<AGG_GRID, 256, 0, stream>>>(h, vs, vd, kmapAll, ssrcS, sdstS); break;
        }
        int gs;
        if (st == 0) gs = (navail >= 8) ? 8 : (navail >= 4) ? 4 : (navail >= 2) ? 2 : 1;
        else gs = (navail < P.nk) ? navail : P.nk;
        for (int done = 0; done < P.nk;) {
            int g = gs;
            if (g > P.nk - done) g = P.nk - done;
            int doGS = (done == 0) ? 1 : 0;
            switch (g) {
                case 8: fused_gather<8><<<AGG_GRID, 256, 0, stream>>>(h, row_ptr, col_idx, dinv, cntf, ssrcS, sdstS, P.nk, done, doGS, aggG, aggS, Abuf); break;
                case 4: fused_gather<4><<<AGG_GRID, 256, 0, stream>>>(h, row_ptr, col_idx, dinv, cntf, ssrcS, sdstS, P.nk, done, doGS, aggG, aggS, Abuf); break;
                case 3: fused_gather<3><<<AGG_GRID, 256, 0, stream>>>(h, row_ptr, col_idx, dinv, cntf, ssrcS, sdstS, P.nk, done, doGS, aggG, aggS, Abuf); break;
                case 2: fused_gather<2><<<AGG_GRID, 256, 0, stream>>>(h, row_ptr, col_idx, dinv, cntf, ssrcS, sdstS, P.nk, done, doGS, aggG, aggS, Abuf); break;
                default: fused_gather<1><<<AGG_GRID, 256, 0, stream>>>(h, row_ptr, col_idx, dinv, cntf, ssrcS, sdstS, P.nk, done, doGS, aggG, aggS, Abuf); break;
            }
            if (st == 0 && g >= 2) {
                for (int p2 = done / 2; p2 < (done + g) / 2; ++p2) {
                    int slot0 = p2 * 2 - done;
                    gemm_combined<<<GEMM_GRID, 256, 0, stream>>>(
                        aggG, aggS, h, Wcp + (size_t)p2 * 12288, bcp + p2 * 64, targ[p2]);
                    gemm_gatout<2><<<GEMM_GRID, 256, 0, stream>>>(
                        Abuf + (size_t)slot0 * NCf, Wg + (size_t)P.ks[p2 * 2] * 4096,
                        Wg + (size_t)P.ks[p2 * 2 + 1] * 4096, targ[p2]);
                }
            } else {
                for (int j = 0; j < g; ++j) {
                    int k = P.ks[done + j];
                    int tg = P.tg[done + j];
                    gemm_combined<<<GEMM_GRID, 256, 0, stream>>>(
                        aggG, aggS, h, Wc + (size_t)k * 12288, bcv + k * 64, targ[tg]);
                    gemm_gatout<1><<<GEMM_GRID, 256, 0, stream>>>(
                        Abuf + (size_t)j * NCf, Wg + (size_t)k * 4096,
                        Wg + (size_t)k * 4096, targ[tg]);
                }
            }
            done += g;
        }
    }

    final_mean<<<(N_NODES * CCH / 4 + 255) / 256, 256, 0, stream>>>(
        (const float4*)sb[0], (const float4*)sb[1], (const float4*)sb[2], (float4*)out);
}

// Round 3
// 898.683 us; speedup vs baseline: 2.8774x; 1.3851x over previous
//
#include <hip/hip_runtime.h>

#define N_NODES 50000
#define N_EDGES 800000
#define CCH 64
#define N_MIX 14

typedef __bf16 bf16x8 __attribute__((ext_vector_type(8)));
typedef float floatx4 __attribute__((ext_vector_type(4)));

__device__ __forceinline__ float leaky(float x) {
    return fmaxf(x, 0.2f * x);
}

// ---------------- weight prep --------------------------------------------
// Wt[k] : 64(out-col) x 256(in-dim) bf16, TRANSPOSED, scale-folded.
//   j<64   : g*w0*gcn_W[j][c]            (G block)
//   j<128  : g*w1*sage_Wl[j-64][c]       (S block)
//   j<192  : g*w1*sage_Wr[j-128][c] + (j-128==c)*(g*w3 + (k>=11 ? 0.25 : 0))
//   j<256  : g*w2*gat_W[j-192][c]        (A block)
// g = 0.25 for k>=9 (final mean folded). The +0.25*I for k in {11,12,13}
// folds final_mean's 0.25*(s2+s3+s4): those k's H-input IS s2/s3/s4.
// bc[k] = g*(w0*gcn_b + w1*sage_b + w2*gat_b)  (fp32)
// vs[k] = gat_W @ a_src (row dots), vd[k] = gat_W @ a_dst (unscaled)
__global__ void prep_weights(const float* __restrict__ alphas,
                             const float* __restrict__ gcn_W, const float* __restrict__ gcn_b,
                             const float* __restrict__ sage_Wl, const float* __restrict__ sage_Wr,
                             const float* __restrict__ sage_b, const float* __restrict__ gat_Wp,
                             const float* __restrict__ a_src, const float* __restrict__ a_dst,
                             const float* __restrict__ gat_b,
                             __bf16* __restrict__ Wt, float* __restrict__ bc,
                             float* __restrict__ vs, float* __restrict__ vd) {
    int k = blockIdx.x;
    __shared__ float w[5];
    if (threadIdx.x == 0) {
        float a[5], m = -1e30f, s = 0.f;
        for (int i = 0; i < 5; ++i) { a[i] = alphas[k * 5 + i]; m = fmaxf(m, a[i]); }
        for (int i = 0; i < 5; ++i) { a[i] = __expf(a[i] - m); s += a[i]; }
        for (int i = 0; i < 5; ++i) w[i] = a[i] / s;
    }
    __syncthreads();
    float gamma = (k >= 9) ? 0.25f : 1.0f;
    float w0 = gamma * w[0], w1 = gamma * w[1], w2 = gamma * w[2], w3 = gamma * w[3];
    float idext = (k >= 11) ? 0.25f : 0.f;
    for (int idx = threadIdx.x; idx < 64 * 256; idx += blockDim.x) {
        int c = idx >> 8, j = idx & 255;
        float v;
        if (j < 64)       v = w0 * gcn_W[k * 4096 + j * 64 + c];
        else if (j < 128) v = w1 * sage_Wl[k * 4096 + (j - 64) * 64 + c];
        else if (j < 192) {
            int jj = j - 128;
            v = w1 * sage_Wr[k * 4096 + jj * 64 + c];
            if (jj == c) v += w3 + idext;
        } else {
            v = w2 * gat_Wp[k * 4096 + (j - 192) * 64 + c];
        }
        Wt[(size_t)k * 16384 + idx] = (__bf16)v;
    }
    if (threadIdx.x < 64) {
        int r = threadIdx.x;
        bc[k * 64 + r] = gamma * (w[0] * gcn_b[k * 64 + r] + w[1] * sage_b[k * 64 + r] +
                                  w[2] * gat_b[k * 64 + r]);
        float s1 = 0.f, s2 = 0.f;
        for (int j = 0; j < 64; ++j) {
            float wv_ = gat_Wp[k * 4096 + r * 64 + j];
            s1 += wv_ * a_src[k * 64 + j];
            s2 += wv_ * a_dst[k * 64 + j];
        }
        vs[k * 64 + r] = s1;
        vd[k * 64 + r] = s2;
    }
}

// ---------------- CSR build ------------------------------------------------
__global__ void count_indeg(const int* __restrict__ ei, int* __restrict__ indeg) {
    int e = blockIdx.x * blockDim.x + threadIdx.x;
    if (e < N_EDGES) atomicAdd(&indeg[ei[N_EDGES + e]], 1);
}

#define NBLK 196  // ceil(50000/256)

__global__ __launch_bounds__(256) void deg_block_reduce(const int* __restrict__ indeg,
                                                        int* __restrict__ bsum) {
    int i = blockIdx.x * 256 + threadIdx.x;
    int v = (i < N_NODES) ? indeg[i] : 0;
#pragma unroll
    for (int off = 1; off < 64; off <<= 1) v += __shfl_xor(v, off, 64);
    __shared__ int ws_[4];
    if ((threadIdx.x & 63) == 0) ws_[threadIdx.x >> 6] = v;
    __syncthreads();
    if (threadIdx.x == 0) bsum[blockIdx.x] = ws_[0] + ws_[1] + ws_[2] + ws_[3];
}

__global__ __launch_bounds__(256) void scan_bsum(int* __restrict__ bsum, int* __restrict__ row_ptr) {
    __shared__ int s[256];
    int t = threadIdx.x;
    int v = (t < NBLK) ? bsum[t] : 0;
    s[t] = v;
    __syncthreads();
    for (int off = 1; off < 256; off <<= 1) {
        int tmp = (t >= off) ? s[t - off] : 0;
        __syncthreads();
        s[t] += tmp;
        __syncthreads();
    }
    if (t < NBLK) bsum[t] = s[t] - v;  // exclusive
    if (t == 0) row_ptr[N_NODES] = s[255];
}

__global__ __launch_bounds__(256) void scan_write(int* __restrict__ indeg,
                                                  const int* __restrict__ bsum,
                                                  int* __restrict__ row_ptr,
                                                  float* __restrict__ dinv,
                                                  float* __restrict__ cntf) {
    int i = blockIdx.x * 256 + threadIdx.x;
    int lane = threadIdx.x & 63, wv = threadIdx.x >> 6;
    int val = (i < N_NODES) ? indeg[i] : 0;
    int inc = val;
#pragma unroll
    for (int off = 1; off < 64; off <<= 1) {
        int t2 = __shfl_up(inc, off, 64);
        if (lane >= off) inc += t2;
    }
    __shared__ int wsum[4];
    if (lane == 63) wsum[wv] = inc;
    __syncthreads();
    int woff = 0;
    for (int j = 0; j < wv; ++j) woff += wsum[j];
    if (i < N_NODES) {
        row_ptr[i] = bsum[blockIdx.x] + woff + inc - val;
        dinv[i] = rsqrtf((float)(val + 1));
        cntf[i] = (float)(val > 0 ? val : 1);
        indeg[i] = 0;  // reuse as fill counter
    }
}

__global__ void fill_csr(const int* __restrict__ ei, const int* __restrict__ row_ptr,
                         int* __restrict__ fill_cnt, int* __restrict__ col_idx) {
    int e = blockIdx.x * blockDim.x + threadIdx.x;
    if (e < N_EDGES) {
        int d = ei[N_EDGES + e];
        int pos = row_ptr[d] + atomicAdd(&fill_cnt[d], 1);
        col_idx[pos] = ei[e];
    }
}

// ---------------- per-state GAT scores -------------------------------------
template <int NK>
__global__ __launch_bounds__(256) void score_kernel(const float* __restrict__ h,
                                                    const float* __restrict__ vs_all,
                                                    const float* __restrict__ vd_all,
                                                    unsigned kmap,
                                                    float* __restrict__ ssrcS,
                                                    float* __restrict__ sdstS) {
    int node = blockIdx.x * 4 + (threadIdx.x >> 6);
    int lane = threadIdx.x & 63;
    if (node >= N_NODES) return;
    float hv = h[(size_t)node * 64 + lane];
#pragma unroll
    for (int t = 0; t < NK; ++t) {
        int k = (kmap >> (4 * t)) & 15;
        float ps = hv * vs_all[k * 64 + lane];
        float pd = hv * vd_all[k * 64 + lane];
#pragma unroll
        for (int off = 1; off < 64; off <<= 1) {
            ps += __shfl_xor(ps, off, 64);
            pd += __shfl_xor(pd, off, 64);
        }
        if (lane == 0) {
            ssrcS[(size_t)node * NK + t] = ps;
            sdstS[(size_t)node * NK + t] = pd;
        }
    }
}

// ---------------- fused per-state gather: GCN + SAGE + NK GAT softmax ------
template <int NK>
__global__ __launch_bounds__(256) void fused_gather(
    const float* __restrict__ h, const int* __restrict__ row_ptr,
    const int* __restrict__ col_idx, const float* __restrict__ dinv,
    const float* __restrict__ cntf, const float* __restrict__ ssrcS,
    const float* __restrict__ sdstS, int snk, int soff, int doGS,
    __bf16* __restrict__ aggG, __bf16* __restrict__ aggS, __bf16* __restrict__ A) {
    int node = blockIdx.x * 4 + (threadIdx.x >> 6);
    int lane = threadIdx.x & 63;
    if (node >= N_NODES) return;
    int beg = row_ptr[node], end = row_ptr[node + 1];
    float sd[NK], m[NK];
#pragma unroll
    for (int t = 0; t < NK; ++t) {
        sd[t] = sdstS[(size_t)node * snk + soff + t];
        m[t] = leaky(ssrcS[(size_t)node * snk + soff + t] + sd[t]);  // self score
    }
    for (int e = beg + lane; e < end; e += 64) {
        int s = col_idx[e];
        const float* sp = ssrcS + (size_t)s * snk + soff;
#pragma unroll
        for (int t = 0; t < NK; ++t) m[t] = fmaxf(m[t], leaky(sp[t] + sd[t]));
    }
#pragma unroll
    for (int t = 0; t < NK; ++t)
#pragma unroll
        for (int off = 1; off < 64; off <<= 1) m[t] = fmaxf(m[t], __shfl_xor(m[t], off, 64));
    float hvself = h[(size_t)node * 64 + lane];
    float denom[NK], acc[NK];
#pragma unroll
    for (int t = 0; t < NK; ++t) {
        float w = __expf(leaky(ssrcS[(size_t)node * snk + soff + t] + sd[t]) - m[t]);
        denom[t] = w;
        acc[t] = w * hvself;
    }
    float sG = 0.f, sS = 0.f;
    for (int base = beg; base < end; base += 64) {
        int cnt = min(64, end - base);
        int col = 0;
        float dv = 0.f, wv[NK];
#pragma unroll
        for (int t = 0; t < NK; ++t) wv[t] = 0.f;
        if (lane < cnt) {
            col = col_idx[base + lane];
            dv = dinv[col];
            const float* sp = ssrcS + (size_t)col * snk + soff;
#pragma unroll
            for (int t = 0; t < NK; ++t) wv[t] = __expf(leaky(sp[t] + sd[t]) - m[t]);
        }
#pragma unroll
        for (int t = 0; t < NK; ++t) {
            float w = wv[t];
#pragma unroll
            for (int off = 1; off < 64; off <<= 1) w += __shfl_xor(w, off, 64);
            denom[t] += w;
        }
        for (int j = 0; j < cnt; ++j) {
            int s = __shfl(col, j, 64);
            float hv = h[(size_t)s * 64 + lane];
            sS += hv;
            sG += __shfl(dv, j, 64) * hv;
#pragma unroll
            for (int t = 0; t < NK; ++t) acc[t] += __shfl(wv[t], j, 64) * hv;
        }
    }
    if (doGS) {
        float dvn = dinv[node];
        aggS[(size_t)node * 64 + lane] = (__bf16)(sS / cntf[node]);
        aggG[(size_t)node * 64 + lane] = (__bf16)(dvn * sG + dvn * dvn * hvself);
    }
#pragma unroll
    for (int t = 0; t < NK; ++t)
        A[(size_t)t * N_NODES * 64 + (size_t)node * 64 + lane] = (__bf16)(acc[t] / denom[t]);
}

// ---------------- MFMA group GEMM: for each k, tgt (+)= [G|S|H|A_k]@Wt_k + bc_k
struct GArgs {
    const __bf16* G;
    const __bf16* S;
    const float* H;
    const __bf16* A0;
    const __bf16* Wt;
    const float* bc;
    float* tg[4];
    long long slot;  // elements per A slot
    int nk;
    int initmask;
    int kidx[8];
    int tsel[8];
};

__global__ __launch_bounds__(256) void gemm_group(GArgs a) {
    __shared__ __bf16 Wl[64 * 264];  // +8 bf16 pad per row: conflict-free b128 reads
    int tid = threadIdx.x;
    int wave = tid >> 6, lane = tid & 63;
    int quad = lane >> 4, mr = lane & 15;
    int r0 = blockIdx.x * 128 + wave * 32;  // this wave: rows r0..r0+31
    for (int t = 0; t < a.nk; ++t) {
        int k = a.kidx[t];
        __syncthreads();  // protect Wl from previous iter's readers
        {
            const uint4* src = (const uint4*)(a.Wt + (size_t)k * 16384);
            for (int i = tid; i < 2048; i += 256) {
                int row = i >> 5, colj = (i & 31) << 3;
                *(uint4*)&Wl[row * 264 + colj] = src[i];
            }
        }
        __syncthreads();
        floatx4 acc[2][4];
#pragma unroll
        for (int rt = 0; rt < 2; ++rt)
#pragma unroll
            for (int ct = 0; ct < 4; ++ct) acc[rt][ct] = (floatx4){0.f, 0.f, 0.f, 0.f};
        const __bf16* Ap = a.A0 + (size_t)t * a.slot;
        for (int kt = 0; kt < 8; ++kt) {
            int seg = kt >> 1;
            int segcol = ((kt & 1) << 5) + (quad << 3);
            bf16x8 af[2];
#pragma unroll
            for (int rt = 0; rt < 2; ++rt) {
                int r = r0 + rt * 16 + mr;
                if (r > N_NODES - 1) r = N_NODES - 1;
                if (seg == 2) {
                    const float* hp = a.H + (size_t)r * 64 + segcol;
                    float4 f0 = *(const float4*)hp, f1 = *(const float4*)(hp + 4);
                    bf16x8 v;
                    v[0] = (__bf16)f0.x; v[1] = (__bf16)f0.y;
                    v[2] = (__bf16)f0.z; v[3] = (__bf16)f0.w;
                    v[4] = (__bf16)f1.x; v[5] = (__bf16)f1.y;
                    v[6] = (__bf16)f1.z; v[7] = (__bf16)f1.w;
                    af[rt] = v;
                } else {
                    const __bf16* bp = (seg == 0) ? a.G : (seg == 1) ? a.S : Ap;
                    af[rt] = *(const bf16x8*)(bp + (size_t)r * 64 + segcol);
                }
            }
#pragma unroll
            for (int ct = 0; ct < 4; ++ct) {
                bf16x8 bfr = *(const bf16x8*)&Wl[(ct * 16 + mr) * 264 + (kt << 5) + (quad << 3)];
                acc[0][ct] = __builtin_amdgcn_mfma_f32_16x16x32_bf16(af[0], bfr, acc[0][ct], 0, 0, 0);
                acc[1][ct] = __builtin_amdgcn_mfma_f32_16x16x32_bf16(af[1], bfr, acc[1][ct], 0, 0, 0);
            }
        }
        // epilogue: C/D layout col=lane&15, row=quad*4+reg
        float* tgt = a.tg[a.tsel[t]];
        const float* bp = a.bc + k * 64;
        int init = (a.initmask >> t) & 1;
#pragma unroll
        for (int rt = 0; rt < 2; ++rt) {
#pragma unroll
            for (int reg = 0; reg < 4; ++reg) {
                int r = r0 + rt * 16 + quad * 4 + reg;
                if (r < N_NODES) {
#pragma unroll
                    for (int ct = 0; ct < 4; ++ct) {
                        int c = ct * 16 + mr;
                        float v = acc[rt][ct][reg] + bp[c];
                        size_t idx = (size_t)r * 64 + c;
                        if (init) tgt[idx] = v;
                        else tgt[idx] += v;
                    }
                }
            }
        }
    }
}

extern "C" void kernel_launch(void* const* d_in, const int* in_sizes, int n_in,
                              void* d_out, int out_size, void* d_ws, size_t ws_size,
                              hipStream_t stream) {
    const float* x       = (const float*)d_in[0];
    const int*   ei      = (const int*)d_in[1];
    const float* alphas  = (const float*)d_in[2];
    const float* gcn_W   = (const float*)d_in[3];
    const float* gcn_b   = (const float*)d_in[4];
    const float* sage_Wl = (const float*)d_in[5];
    const float* sage_Wr = (const float*)d_in[6];
    const float* sage_b  = (const float*)d_in[7];
    const float* gat_W   = (const float*)d_in[8];
    const float* a_src   = (const float*)d_in[9];
    const float* a_dst   = (const float*)d_in[10];
    const float* gat_b   = (const float*)d_in[11];
    float* out = (float*)d_out;

    char* p = (char*)d_ws;
    auto alloc = [&](size_t bytes) -> char* {
        char* r = p;
        p += (bytes + 255) & ~(size_t)255;
        return r;
    };
    const size_t NCf = (size_t)N_NODES * CCH;       // elements
    const size_t NC32 = NCf * 4;                    // fp32 bytes
    const size_t NC16 = NCf * 2;                    // bf16 bytes
    float* sb[3];
    sb[0] = (float*)alloc(NC32);
    sb[1] = (float*)alloc(NC32);
    sb[2] = (float*)alloc(NC32);
    __bf16* aggG = (__bf16*)alloc(NC16);
    __bf16* aggS = (__bf16*)alloc(NC16);
    float* ssrcS = (float*)alloc((size_t)N_NODES * 8 * 4);
    float* sdstS = (float*)alloc((size_t)N_NODES * 8 * 4);
    float* dinv  = (float*)alloc(N_NODES * 4);
    float* cntf  = (float*)alloc(N_NODES * 4);
    int* row_ptr = (int*)alloc((N_NODES + 1) * 4);
    int* col_idx = (int*)alloc((size_t)N_EDGES * 4);
    int* indeg   = (int*)alloc(N_NODES * 4);
    int* bsum    = (int*)alloc(NBLK * 4);
    __bf16* Wt   = (__bf16*)alloc((size_t)N_MIX * 16384 * 2);
    float* bcv   = (float*)alloc(N_MIX * 64 * 4);
    float* vs    = (float*)alloc(N_MIX * 64 * 4);
    float* vd    = (float*)alloc(N_MIX * 64 * 4);

    size_t used = (size_t)(p - (char*)d_ws);
    int navail = (int)((ws_size > used) ? ((ws_size - used) / NC16) : 0);
    if (navail < 1) navail = 1;
    if (navail > 8) navail = 8;
    __bf16* Abuf = (__bf16*)alloc((size_t)navail * NC16);

    hipMemsetAsync(indeg, 0, N_NODES * 4, stream);

    prep_weights<<<N_MIX, 256, 0, stream>>>(alphas, gcn_W, gcn_b, sage_Wl, sage_Wr, sage_b,
                                            gat_W, a_src, a_dst, gat_b, Wt, bcv, vs, vd);
    count_indeg<<<(N_EDGES + 255) / 256, 256, 0, stream>>>(ei, indeg);
    deg_block_reduce<<<NBLK, 256, 0, stream>>>(indeg, bsum);
    scan_bsum<<<1, 256, 0, stream>>>(bsum, row_ptr);
    scan_write<<<NBLK, 256, 0, stream>>>(indeg, bsum, row_ptr, dinv, cntf);
    fill_csr<<<(N_EDGES + 255) / 256, 256, 0, stream>>>(ei, row_ptr, indeg, col_idx);

    const int AGG_GRID = (N_NODES + 3) / 4;       // 12500
    const int GEMM_GRID = (N_NODES + 127) / 128;  // 391

    float* targ[4] = {sb[0], sb[1], sb[2], out};
    struct Phase { int nk; int ks[8]; int tg[8]; };
    const Phase ph[4] = {
        {8, {0, 1, 2, 3, 5, 6, 9, 10}, {0, 0, 1, 1, 2, 2, 3, 3}},
        {3, {4, 7, 11, 0, 0, 0, 0, 0}, {1, 2, 3, 0, 0, 0, 0, 0}},
        {2, {8, 12, 0, 0, 0, 0, 0, 0}, {2, 3, 0, 0, 0, 0, 0, 0}},
        {1, {13, 0, 0, 0, 0, 0, 0, 0}, {3, 0, 0, 0, 0, 0, 0, 0}},
    };

    for (int st = 0; st < 4; ++st) {
        const Phase& P = ph[st];
        const float* h = (st == 0) ? x : sb[st - 1];
        unsigned kmapAll = 0;
        for (int t = 0; t < P.nk; ++t) kmapAll |= (unsigned)P.ks[t] << (4 * t);
        switch (P.nk) {
            case 8: score_kernel<8><<<AGG_GRID, 256, 0, stream>>>(h, vs, vd, kmapAll, ssrcS, sdstS); break;
            case 3: score_kernel<3><<<AGG_GRID, 256, 0, stream>>>(h, vs, vd, kmapAll, ssrcS, sdstS); break;
            case 2: score_kernel<2><<<AGG_GRID, 256, 0, stream>>>(h, vs, vd, kmapAll, ssrcS, sdstS); break;
            default: score_kernel<1><<<AGG_GRID, 256, 0, stream>>>(h, vs, vd, kmapAll, ssrcS, sdstS); break;
        }
        int gs;
        if (st == 0) gs = (navail >= 8) ? 8 : (navail >= 4) ? 4 : (navail >= 2) ? 2 : 1;
        else gs = (navail < P.nk) ? navail : P.nk;
        for (int done = 0; done < P.nk;) {
            int g = gs;
            if (g > P.nk - done) g = P.nk - done;
            int doGS = (done == 0) ? 1 : 0;
            switch (g) {
                case 8: fused_gather<8><<<AGG_GRID, 256, 0, stream>>>(h, row_ptr, col_idx, dinv, cntf, ssrcS, sdstS, P.nk, done, doGS, aggG, aggS, Abuf); break;
                case 4: fused_gather<4><<<AGG_GRID, 256, 0, stream>>>(h, row_ptr, col_idx, dinv, cntf, ssrcS, sdstS, P.nk, done, doGS, aggG, aggS, Abuf); break;
                case 3: fused_gather<3><<<AGG_GRID, 256, 0, stream>>>(h, row_ptr, col_idx, dinv, cntf, ssrcS, sdstS, P.nk, done, doGS, aggG, aggS, Abuf); break;
                case 2: fused_gather<2><<<AGG_GRID, 256, 0, stream>>>(h, row_ptr, col_idx, dinv, cntf, ssrcS, sdstS, P.nk, done, doGS, aggG, aggS, Abuf); break;
                default: fused_gather<1><<<AGG_GRID, 256, 0, stream>>>(h, row_ptr, col_idx, dinv, cntf, ssrcS, sdstS, P.nk, done, doGS, aggG, aggS, Abuf); break;
            }
            GArgs ga;
            ga.G = aggG; ga.S = aggS; ga.H = h; ga.A0 = Abuf;
            ga.Wt = Wt; ga.bc = bcv;
            for (int i = 0; i < 4; ++i) ga.tg[i] = targ[i];
            ga.slot = (long long)NCf;
            ga.nk = g;
            ga.initmask = 0;
            for (int j = 0; j < g; ++j) {
                int k = P.ks[done + j];
                ga.kidx[j] = k;
                ga.tsel[j] = P.tg[done + j];
                if (k == 0 || k == 2 || k == 5 || k == 9) ga.initmask |= (1 << j);
            }
            for (int j = g; j < 8; ++j) { ga.kidx[j] = 0; ga.tsel[j] = 0; }
            gemm_group<<<GEMM_GRID, 256, 0, stream>>>(ga);
            done += g;
        }
    }
}

// Round 4
// 694.296 us; speedup vs baseline: 3.7245x; 1.2944x over previous
//
#include <hip/hip_runtime.h>

#define N_NODES 50000
#define N_EDGES 800000
#define CCH 64
#define N_MIX 14

typedef __bf16 bf16x8 __attribute__((ext_vector_type(8)));
typedef float floatx4 __attribute__((ext_vector_type(4)));

__device__ __forceinline__ float leaky(float x) {
    return fmaxf(x, 0.2f * x);
}

// ---------------- weight prep --------------------------------------------
// Wt[k] : 64(out-col) x 256(in-dim) bf16, transposed, scale-folded.
//   j<64: g*w0*gcn_W ; j<128: g*w1*sage_Wl ;
//   j<192: g*w1*sage_Wr + I*(g*w3 + (k>=11 ? 0.25 : 0)) ; j<256: g*w2*gat_W
// g=0.25 for k>=9 (final mean folded); +0.25*I for k in {11,12,13} folds
// final_mean's 0.25*(s2+s3+s4) since those k's H-input IS s2/s3/s4.
__global__ void prep_weights(const float* __restrict__ alphas,
                             const float* __restrict__ gcn_W, const float* __restrict__ gcn_b,
                             const float* __restrict__ sage_Wl, const float* __restrict__ sage_Wr,
                             const float* __restrict__ sage_b, const float* __restrict__ gat_Wp,
                             const float* __restrict__ a_src, const float* __restrict__ a_dst,
                             const float* __restrict__ gat_b,
                             __bf16* __restrict__ Wt, float* __restrict__ bc,
                             float* __restrict__ vs, float* __restrict__ vd) {
    int k = blockIdx.x;
    __shared__ float w[5];
    if (threadIdx.x == 0) {
        float a[5], m = -1e30f, s = 0.f;
        for (int i = 0; i < 5; ++i) { a[i] = alphas[k * 5 + i]; m = fmaxf(m, a[i]); }
        for (int i = 0; i < 5; ++i) { a[i] = __expf(a[i] - m); s += a[i]; }
        for (int i = 0; i < 5; ++i) w[i] = a[i] / s;
    }
    __syncthreads();
    float gamma = (k >= 9) ? 0.25f : 1.0f;
    float w0 = gamma * w[0], w1 = gamma * w[1], w2 = gamma * w[2], w3 = gamma * w[3];
    float idext = (k >= 11) ? 0.25f : 0.f;
    for (int idx = threadIdx.x; idx < 64 * 256; idx += blockDim.x) {
        int c = idx >> 8, j = idx & 255;
        float v;
        if (j < 64)       v = w0 * gcn_W[k * 4096 + j * 64 + c];
        else if (j < 128) v = w1 * sage_Wl[k * 4096 + (j - 64) * 64 + c];
        else if (j < 192) {
            int jj = j - 128;
            v = w1 * sage_Wr[k * 4096 + jj * 64 + c];
            if (jj == c) v += w3 + idext;
        } else {
            v = w2 * gat_Wp[k * 4096 + (j - 192) * 64 + c];
        }
        Wt[(size_t)k * 16384 + idx] = (__bf16)v;
    }
    if (threadIdx.x < 64) {
        int r = threadIdx.x;
        bc[k * 64 + r] = gamma * (w[0] * gcn_b[k * 64 + r] + w[1] * sage_b[k * 64 + r] +
                                  w[2] * gat_b[k * 64 + r]);
        float s1 = 0.f, s2 = 0.f;
        for (int j = 0; j < 64; ++j) {
            float wv_ = gat_Wp[k * 4096 + r * 64 + j];
            s1 += wv_ * a_src[k * 64 + j];
            s2 += wv_ * a_dst[k * 64 + j];
        }
        vs[k * 64 + r] = s1;
        vd[k * 64 + r] = s2;
    }
}

// ---------------- CSR build ------------------------------------------------
__global__ void count_indeg(const int* __restrict__ ei, int* __restrict__ indeg) {
    int e = blockIdx.x * blockDim.x + threadIdx.x;
    if (e < N_EDGES) atomicAdd(&indeg[ei[N_EDGES + e]], 1);
}

#define NBLK 196  // ceil(50000/256)

__global__ __launch_bounds__(256) void deg_block_reduce(const int* __restrict__ indeg,
                                                        int* __restrict__ bsum) {
    int i = blockIdx.x * 256 + threadIdx.x;
    int v = (i < N_NODES) ? indeg[i] : 0;
#pragma unroll
    for (int off = 1; off < 64; off <<= 1) v += __shfl_xor(v, off, 64);
    __shared__ int ws_[4];
    if ((threadIdx.x & 63) == 0) ws_[threadIdx.x >> 6] = v;
    __syncthreads();
    if (threadIdx.x == 0) bsum[blockIdx.x] = ws_[0] + ws_[1] + ws_[2] + ws_[3];
}

__global__ __launch_bounds__(256) void scan_bsum(int* __restrict__ bsum, int* __restrict__ row_ptr) {
    __shared__ int s[256];
    int t = threadIdx.x;
    int v = (t < NBLK) ? bsum[t] : 0;
    s[t] = v;
    __syncthreads();
    for (int off = 1; off < 256; off <<= 1) {
        int tmp = (t >= off) ? s[t - off] : 0;
        __syncthreads();
        s[t] += tmp;
        __syncthreads();
    }
    if (t < NBLK) bsum[t] = s[t] - v;  // exclusive
    if (t == 0) row_ptr[N_NODES] = s[255];
}

__global__ __launch_bounds__(256) void scan_write(int* __restrict__ indeg,
                                                  const int* __restrict__ bsum,
                                                  int* __restrict__ row_ptr,
                                                  float* __restrict__ dinv,
                                                  float* __restrict__ cntf) {
    int i = blockIdx.x * 256 + threadIdx.x;
    int lane = threadIdx.x & 63, wv = threadIdx.x >> 6;
    int val = (i < N_NODES) ? indeg[i] : 0;
    int inc = val;
#pragma unroll
    for (int off = 1; off < 64; off <<= 1) {
        int t2 = __shfl_up(inc, off, 64);
        if (lane >= off) inc += t2;
    }
    __shared__ int wsum[4];
    if (lane == 63) wsum[wv] = inc;
    __syncthreads();
    int woff = 0;
    for (int j = 0; j < wv; ++j) woff += wsum[j];
    if (i < N_NODES) {
        row_ptr[i] = bsum[blockIdx.x] + woff + inc - val;
        dinv[i] = rsqrtf((float)(val + 1));
        cntf[i] = (float)(val > 0 ? val : 1);
        indeg[i] = 0;  // reuse as fill counter
    }
}

__global__ void fill_csr(const int* __restrict__ ei, const int* __restrict__ row_ptr,
                         int* __restrict__ fill_cnt, int* __restrict__ col_idx) {
    int e = blockIdx.x * blockDim.x + threadIdx.x;
    if (e < N_EDGES) {
        int d = ei[N_EDGES + e];
        int pos = row_ptr[d] + atomicAdd(&fill_cnt[d], 1);
        col_idx[pos] = ei[e];
    }
}

// ---------------- per-state GAT scores -------------------------------------
template <int NK>
__global__ __launch_bounds__(256) void score_kernel(const float* __restrict__ h,
                                                    const float* __restrict__ vs_all,
                                                    const float* __restrict__ vd_all,
                                                    unsigned kmap,
                                                    float* __restrict__ ssrcS,
                                                    float* __restrict__ sdstS) {
    int node = blockIdx.x * 4 + (threadIdx.x >> 6);
    int lane = threadIdx.x & 63;
    if (node >= N_NODES) return;
    float hv = h[(size_t)node * 64 + lane];
#pragma unroll
    for (int t = 0; t < NK; ++t) {
        int k = (kmap >> (4 * t)) & 15;
        float ps = hv * vs_all[k * 64 + lane];
        float pd = hv * vd_all[k * 64 + lane];
#pragma unroll
        for (int off = 1; off < 64; off <<= 1) {
            ps += __shfl_xor(ps, off, 64);
            pd += __shfl_xor(pd, off, 64);
        }
        if (lane == 0) {
            ssrcS[(size_t)node * NK + t] = ps;
            sdstS[(size_t)node * NK + t] = pd;
        }
    }
}

// ---------------- fused per-state gather: GCN + SAGE + NK GAT softmax ------
// One wave per node, lane = channel. Fast path (deg<=64): one chunk preload
// computes raw scores once (no separate max pass), then 4-way batched feature
// loads for MLP. Generic fallback: two-pass as before.
template <int NK>
__global__ __launch_bounds__(256) void fused_gather(
    const float* __restrict__ h, const int* __restrict__ row_ptr,
    const int* __restrict__ col_idx, const float* __restrict__ dinv,
    const float* __restrict__ cntf, const float* __restrict__ ssrcS,
    const float* __restrict__ sdstS, int snk, int soff, int doGS,
    __bf16* __restrict__ aggG, __bf16* __restrict__ aggS, __bf16* __restrict__ A) {
    int node = blockIdx.x * 4 + (threadIdx.x >> 6);
    int lane = threadIdx.x & 63;
    if (node >= N_NODES) return;
    int beg = row_ptr[node], end = row_ptr[node + 1];
    int deg = end - beg;
    const float* ssn = ssrcS + (size_t)node * snk + soff;
    const float* sdn = sdstS + (size_t)node * snk + soff;
    float sd[NK], selfraw[NK];
#pragma unroll
    for (int t = 0; t < NK; ++t) {
        sd[t] = sdn[t];
        selfraw[t] = leaky(ssn[t] + sd[t]);
    }
    float hvself = h[(size_t)node * 64 + lane];
    float sG = 0.f, sS = 0.f;
    float denom[NK], acc[NK];

    if (deg <= 64) {
        int col = 0;
        float dv = 0.f, wv[NK];
#pragma unroll
        for (int t = 0; t < NK; ++t) wv[t] = -1e30f;  // holds raw scores first
        if (lane < deg) {
            col = col_idx[beg + lane];
            dv = dinv[col];
            const float* sp = ssrcS + (size_t)col * snk + soff;
#pragma unroll
            for (int t = 0; t < NK; ++t) wv[t] = leaky(sp[t] + sd[t]);
        }
#pragma unroll
        for (int t = 0; t < NK; ++t) {
            float mm = wv[t];
#pragma unroll
            for (int off = 1; off < 64; off <<= 1) mm = fmaxf(mm, __shfl_xor(mm, off, 64));
            mm = fmaxf(mm, selfraw[t]);
            wv[t] = (lane < deg) ? __expf(wv[t] - mm) : 0.f;
            float w = wv[t];
#pragma unroll
            for (int off = 1; off < 64; off <<= 1) w += __shfl_xor(w, off, 64);
            float ws = __expf(selfraw[t] - mm);
            denom[t] = w + ws;
            acc[t] = ws * hvself;
        }
        int j = 0;
        for (; j + 4 <= deg; j += 4) {
            int s0 = __shfl(col, j, 64), s1 = __shfl(col, j + 1, 64);
            int s2 = __shfl(col, j + 2, 64), s3 = __shfl(col, j + 3, 64);
            float h0 = h[(size_t)s0 * 64 + lane];
            float h1 = h[(size_t)s1 * 64 + lane];
            float h2 = h[(size_t)s2 * 64 + lane];
            float h3 = h[(size_t)s3 * 64 + lane];
            sS += (h0 + h1) + (h2 + h3);
            sG += __shfl(dv, j, 64) * h0 + __shfl(dv, j + 1, 64) * h1 +
                  __shfl(dv, j + 2, 64) * h2 + __shfl(dv, j + 3, 64) * h3;
#pragma unroll
            for (int t = 0; t < NK; ++t)
                acc[t] += __shfl(wv[t], j, 64) * h0 + __shfl(wv[t], j + 1, 64) * h1 +
                          __shfl(wv[t], j + 2, 64) * h2 + __shfl(wv[t], j + 3, 64) * h3;
        }
        for (; j < deg; ++j) {
            int s0 = __shfl(col, j, 64);
            float h0 = h[(size_t)s0 * 64 + lane];
            sS += h0;
            sG += __shfl(dv, j, 64) * h0;
#pragma unroll
            for (int t = 0; t < NK; ++t) acc[t] += __shfl(wv[t], j, 64) * h0;
        }
    } else {
        // generic two-pass path (rare: deg > 64)
        float m[NK];
#pragma unroll
        for (int t = 0; t < NK; ++t) m[t] = selfraw[t];
        for (int e = beg + lane; e < end; e += 64) {
            int s = col_idx[e];
            const float* sp = ssrcS + (size_t)s * snk + soff;
#pragma unroll
            for (int t = 0; t < NK; ++t) m[t] = fmaxf(m[t], leaky(sp[t] + sd[t]));
        }
#pragma unroll
        for (int t = 0; t < NK; ++t) {
#pragma unroll
            for (int off = 1; off < 64; off <<= 1) m[t] = fmaxf(m[t], __shfl_xor(m[t], off, 64));
            float ws = __expf(selfraw[t] - m[t]);
            denom[t] = ws;
            acc[t] = ws * hvself;
        }
        for (int base = beg; base < end; base += 64) {
            int cnt = min(64, end - base);
            int col = 0;
            float dv = 0.f, wv[NK];
#pragma unroll
            for (int t = 0; t < NK; ++t) wv[t] = 0.f;
            if (lane < cnt) {
                col = col_idx[base + lane];
                dv = dinv[col];
                const float* sp = ssrcS + (size_t)col * snk + soff;
#pragma unroll
                for (int t = 0; t < NK; ++t) wv[t] = __expf(leaky(sp[t] + sd[t]) - m[t]);
            }
#pragma unroll
            for (int t = 0; t < NK; ++t) {
                float w = wv[t];
#pragma unroll
                for (int off = 1; off < 64; off <<= 1) w += __shfl_xor(w, off, 64);
                denom[t] += w;
            }
            for (int j = 0; j < cnt; ++j) {
                int s = __shfl(col, j, 64);
                float hv = h[(size_t)s * 64 + lane];
                sS += hv;
                sG += __shfl(dv, j, 64) * hv;
#pragma unroll
                for (int t = 0; t < NK; ++t) acc[t] += __shfl(wv[t], j, 64) * hv;
            }
        }
    }
    if (doGS) {
        float dvn = dinv[node];
        aggS[(size_t)node * 64 + lane] = (__bf16)(sS / cntf[node]);
        aggG[(size_t)node * 64 + lane] = (__bf16)(dvn * sG + dvn * dvn * hvself);
    }
#pragma unroll
    for (int t = 0; t < NK; ++t)
        A[(size_t)t * N_NODES * 64 + (size_t)node * 64 + lane] = (__bf16)(acc[t] / denom[t]);
}

// ---------------- MFMA group GEMM ------------------------------------------
// For each k in group: tgt (+)= [G|S|H|A_k] @ Wt_k + bc_k.
// G/S/H fragments loaded ONCE (k-invariant); consecutive k's sharing a target
// accumulate in-register and flush once (init-write kills RMW read).
struct GArgs {
    const __bf16* G;
    const __bf16* S;
    const float* H;
    const __bf16* A0;
    const __bf16* Wt;
    const float* bc;
    float* tg[4];
    long long slot;
    int nk;
    int initmask;  // bit t: run starting at t does init-write
    int kidx[8];
    int tsel[8];
};

__global__ __launch_bounds__(256) void gemm_group(GArgs a) {
    __shared__ __bf16 Wl[64 * 264];  // +8 bf16 pad per row
    int tid = threadIdx.x;
    int wave = tid >> 6, lane = tid & 63;
    int quad = lane >> 4, mr = lane & 15;
    int r0 = blockIdx.x * 128 + wave * 32;
    // k-invariant A-operand fragments
    bf16x8 gf[2][2], sf[2][2], hf[2][2];
#pragma unroll
    for (int rt = 0; rt < 2; ++rt) {
        int r = r0 + rt * 16 + mr;
        if (r > N_NODES - 1) r = N_NODES - 1;
#pragma unroll
        for (int hh = 0; hh < 2; ++hh) {
            int colj = hh * 32 + (quad << 3);
            gf[rt][hh] = *(const bf16x8*)(a.G + (size_t)r * 64 + colj);
            sf[rt][hh] = *(const bf16x8*)(a.S + (size_t)r * 64 + colj);
            const float* hp = a.H + (size_t)r * 64 + colj;
            float4 f0 = *(const float4*)hp, f1 = *(const float4*)(hp + 4);
            bf16x8 v;
            v[0] = (__bf16)f0.x; v[1] = (__bf16)f0.y;
            v[2] = (__bf16)f0.z; v[3] = (__bf16)f0.w;
            v[4] = (__bf16)f1.x; v[5] = (__bf16)f1.y;
            v[6] = (__bf16)f1.z; v[7] = (__bf16)f1.w;
            hf[rt][hh] = v;
        }
    }
    floatx4 acc[2][4];
    float bsum[4];
#pragma unroll
    for (int rt = 0; rt < 2; ++rt)
#pragma unroll
        for (int ct = 0; ct < 4; ++ct) acc[rt][ct] = (floatx4){0.f, 0.f, 0.f, 0.f};
#pragma unroll
    for (int ct = 0; ct < 4; ++ct) bsum[ct] = 0.f;
    int runstart = 0;
    for (int t = 0; t < a.nk; ++t) {
        int k = a.kidx[t];
        __syncthreads();
        {
            const uint4* src = (const uint4*)(a.Wt + (size_t)k * 16384);
            for (int i = tid; i < 2048; i += 256) {
                int row = i >> 5, colj = (i & 31) << 3;
                *(uint4*)&Wl[row * 264 + colj] = src[i];
            }
        }
        __syncthreads();
        const __bf16* Ap = a.A0 + (size_t)t * a.slot;
        bf16x8 af[2][2];
#pragma unroll
        for (int rt = 0; rt < 2; ++rt) {
            int r = r0 + rt * 16 + mr;
            if (r > N_NODES - 1) r = N_NODES - 1;
#pragma unroll
            for (int hh = 0; hh < 2; ++hh)
                af[rt][hh] = *(const bf16x8*)(Ap + (size_t)r * 64 + hh * 32 + (quad << 3));
        }
        const float* bp = a.bc + k * 64;
#pragma unroll
        for (int ct = 0; ct < 4; ++ct) bsum[ct] += bp[ct * 16 + mr];
#pragma unroll
        for (int seg = 0; seg < 4; ++seg) {
#pragma unroll
            for (int hh = 0; hh < 2; ++hh) {
                int kt = seg * 2 + hh;
                bf16x8 a0 = (seg == 0) ? gf[0][hh] : (seg == 1) ? sf[0][hh]
                            : (seg == 2) ? hf[0][hh] : af[0][hh];
                bf16x8 a1 = (seg == 0) ? gf[1][hh] : (seg == 1) ? sf[1][hh]
                            : (seg == 2) ? hf[1][hh] : af[1][hh];
#pragma unroll
                for (int ct = 0; ct < 4; ++ct) {
                    bf16x8 bfr = *(const bf16x8*)&Wl[(ct * 16 + mr) * 264 + (kt << 5) + (quad << 3)];
                    acc[0][ct] = __builtin_amdgcn_mfma_f32_16x16x32_bf16(a0, bfr, acc[0][ct], 0, 0, 0);
                    acc[1][ct] = __builtin_amdgcn_mfma_f32_16x16x32_bf16(a1, bfr, acc[1][ct], 0, 0, 0);
                }
            }
        }
        bool flush = (t == a.nk - 1) || (a.tsel[t + 1] != a.tsel[t]);
        if (flush) {
            float* tgt = a.tg[a.tsel[t]];
            int init = (a.initmask >> runstart) & 1;
#pragma unroll
            for (int rt = 0; rt < 2; ++rt) {
#pragma unroll
                for (int reg = 0; reg < 4; ++reg) {
                    int r = r0 + rt * 16 + quad * 4 + reg;
                    if (r < N_NODES) {
#pragma unroll
                        for (int ct = 0; ct < 4; ++ct) {
                            int c = ct * 16 + mr;
                            float v = acc[rt][ct][reg] + bsum[ct];
                            size_t idx = (size_t)r * 64 + c;
                            if (init) tgt[idx] = v;
                            else tgt[idx] += v;
                        }
                    }
                }
            }
#pragma unroll
            for (int rt = 0; rt < 2; ++rt)
#pragma unroll
                for (int ct = 0; ct < 4; ++ct) acc[rt][ct] = (floatx4){0.f, 0.f, 0.f, 0.f};
#pragma unroll
            for (int ct = 0; ct < 4; ++ct) bsum[ct] = 0.f;
            runstart = t + 1;
        }
    }
}

extern "C" void kernel_launch(void* const* d_in, const int* in_sizes, int n_in,
                              void* d_out, int out_size, void* d_ws, size_t ws_size,
                              hipStream_t stream) {
    const float* x       = (const float*)d_in[0];
    const int*   ei      = (const int*)d_in[1];
    const float* alphas  = (const float*)d_in[2];
    const float* gcn_W   = (const float*)d_in[3];
    const float* gcn_b   = (const float*)d_in[4];
    const float* sage_Wl = (const float*)d_in[5];
    const float* sage_Wr = (const float*)d_in[6];
    const float* sage_b  = (const float*)d_in[7];
    const float* gat_W   = (const float*)d_in[8];
    const float* a_src   = (const float*)d_in[9];
    const float* a_dst   = (const float*)d_in[10];
    const float* gat_b   = (const float*)d_in[11];
    float* out = (float*)d_out;

    char* p = (char*)d_ws;
    auto alloc = [&](size_t bytes) -> char* {
        char* r = p;
        p += (bytes + 255) & ~(size_t)255;
        return r;
    };
    const size_t NCf = (size_t)N_NODES * CCH;
    const size_t NC32 = NCf * 4;
    const size_t NC16 = NCf * 2;
    float* sb[3];
    sb[0] = (float*)alloc(NC32);
    sb[1] = (float*)alloc(NC32);
    sb[2] = (float*)alloc(NC32);
    __bf16* aggG = (__bf16*)alloc(NC16);
    __bf16* aggS = (__bf16*)alloc(NC16);
    float* ssrcS = (float*)alloc((size_t)N_NODES * 8 * 4);
    float* sdstS = (float*)alloc((size_t)N_NODES * 8 * 4);
    float* dinv  = (float*)alloc(N_NODES * 4);
    float* cntf  = (float*)alloc(N_NODES * 4);
    int* row_ptr = (int*)alloc((N_NODES + 1) * 4);
    int* col_idx = (int*)alloc((size_t)N_EDGES * 4);
    int* indeg   = (int*)alloc(N_NODES * 4);
    int* bsum    = (int*)alloc(NBLK * 4);
    __bf16* Wt   = (__bf16*)alloc((size_t)N_MIX * 16384 * 2);
    float* bcv   = (float*)alloc(N_MIX * 64 * 4);
    float* vs    = (float*)alloc(N_MIX * 64 * 4);
    float* vd    = (float*)alloc(N_MIX * 64 * 4);

    size_t used = (size_t)(p - (char*)d_ws);
    int navail = (int)((ws_size > used) ? ((ws_size - used) / NC16) : 0);
    if (navail < 1) navail = 1;
    if (navail > 8) navail = 8;
    __bf16* Abuf = (__bf16*)alloc((size_t)navail * NC16);

    hipMemsetAsync(indeg, 0, N_NODES * 4, stream);

    prep_weights<<<N_MIX, 256, 0, stream>>>(alphas, gcn_W, gcn_b, sage_Wl, sage_Wr, sage_b,
                                            gat_W, a_src, a_dst, gat_b, Wt, bcv, vs, vd);
    count_indeg<<<(N_EDGES + 255) / 256, 256, 0, stream>>>(ei, indeg);
    deg_block_reduce<<<NBLK, 256, 0, stream>>>(indeg, bsum);
    scan_bsum<<<1, 256, 0, stream>>>(bsum, row_ptr);
    scan_write<<<NBLK, 256, 0, stream>>>(indeg, bsum, row_ptr, dinv, cntf);
    fill_csr<<<(N_EDGES + 255) / 256, 256, 0, stream>>>(ei, row_ptr, indeg, col_idx);

    const int AGG_GRID = (N_NODES + 3) / 4;       // 12500
    const int GEMM_GRID = (N_NODES + 127) / 128;  // 391

    float* targ[4] = {sb[0], sb[1], sb[2], out};
    struct Phase { int nk; int ks[8]; int tg[8]; };
    const Phase ph[4] = {
        {8, {0, 1, 2, 3, 5, 6, 9, 10}, {0, 0, 1, 1, 2, 2, 3, 3}},
        {3, {4, 7, 11, 0, 0, 0, 0, 0}, {1, 2, 3, 0, 0, 0, 0, 0}},
        {2, {8, 12, 0, 0, 0, 0, 0, 0}, {2, 3, 0, 0, 0, 0, 0, 0}},
        {1, {13, 0, 0, 0, 0, 0, 0, 0}, {3, 0, 0, 0, 0, 0, 0, 0}},
    };

    for (int st = 0; st < 4; ++st) {
        const Phase& P = ph[st];
        const float* h = (st == 0) ? x : sb[st - 1];
        unsigned kmapAll = 0;
        for (int t = 0; t < P.nk; ++t) kmapAll |= (unsigned)P.ks[t] << (4 * t);
        switch (P.nk) {
            case 8: score_kernel<8><<<AGG_GRID, 256, 0, stream>>>(h, vs, vd, kmapAll, ssrcS, sdstS); break;
            case 3: score_kernel<3><<<AGG_GRID, 256, 0, stream>>>(h, vs, vd, kmapAll, ssrcS, sdstS); break;
            case 2: score_kernel<2><<<AGG_GRID, 256, 0, stream>>>(h, vs, vd, kmapAll, ssrcS, sdstS); break;
            default: score_kernel<1><<<AGG_GRID, 256, 0, stream>>>(h, vs, vd, kmapAll, ssrcS, sdstS); break;
        }
        int gs;
        if (st == 0) gs = (navail >= 8) ? 8 : (navail >= 4) ? 4 : (navail >= 2) ? 2 : 1;
        else gs = (navail < P.nk) ? navail : P.nk;
        for (int done = 0; done < P.nk;) {
            int g = gs;
            if (g > P.nk - done) g = P.nk - done;
            int doGS = (done == 0) ? 1 : 0;
            switch (g) {
                case 8: fused_gather<8><<<AGG_GRID, 256, 0, stream>>>(h, row_ptr, col_idx, dinv, cntf, ssrcS, sdstS, P.nk, done, doGS, aggG, aggS, Abuf); break;
                case 4: fused_gather<4><<<AGG_GRID, 256, 0, stream>>>(h, row_ptr, col_idx, dinv, cntf, ssrcS, sdstS, P.nk, done, doGS, aggG, aggS, Abuf); break;
                case 3: fused_gather<3><<<AGG_GRID, 256, 0, stream>>>(h, row_ptr, col_idx, dinv, cntf, ssrcS, sdstS, P.nk, done, doGS, aggG, aggS, Abuf); break;
                case 2: fused_gather<2><<<AGG_GRID, 256, 0, stream>>>(h, row_ptr, col_idx, dinv, cntf, ssrcS, sdstS, P.nk, done, doGS, aggG, aggS, Abuf); break;
                default: fused_gather<1><<<AGG_GRID, 256, 0, stream>>>(h, row_ptr, col_idx, dinv, cntf, ssrcS, sdstS, P.nk, done, doGS, aggG, aggS, Abuf); break;
            }
            GArgs ga;
            ga.G = aggG; ga.S = aggS; ga.H = h; ga.A0 = Abuf;
            ga.Wt = Wt; ga.bc = bcv;
            for (int i = 0; i < 4; ++i) ga.tg[i] = targ[i];
            ga.slot = (long long)NCf;
            ga.nk = g;
            ga.initmask = 0;
            for (int j = 0; j < g; ++j) {
                int k = P.ks[done + j];
                ga.kidx[j] = k;
                ga.tsel[j] = P.tg[done + j];
                if (k == 0 || k == 2 || k == 5 || k == 9) ga.initmask |= (1 << j);
            }
            for (int j = g; j < 8; ++j) { ga.kidx[j] = 0; ga.tsel[j] = (j > 0) ? ga.tsel[j - 1] : 0; }
            gemm_group<<<GEMM_GRID, 256, 0, stream>>>(ga);
            done += g;
        }
    }
}